// Round 1
// 6223.991 us; speedup vs baseline: 1.0507x; 1.0507x over previous
//
#include <hip/hip_runtime.h>

typedef __attribute__((ext_vector_type(8))) __bf16 bf16x8;
typedef __attribute__((ext_vector_type(4))) __bf16 bf16x4;
typedef __attribute__((ext_vector_type(4))) float f32x4;
typedef unsigned long long u64;

#define OUT_HT (64ll*512*1024)
#define OUT_CT (OUT_HT + 64*1024)

// ---------------- prep: x fp32 -> bf16 (same [b][t][i] layout) ----------------
__global__ void convert_x(const float4* __restrict__ in, bf16x4* __restrict__ outp) {
    int i = blockIdx.x * 256 + threadIdx.x;      // 32768 * 256 threads, 1 float4 each
    float4 v = in[i];
    bf16x4 o;
    o[0] = (__bf16)v.x; o[1] = (__bf16)v.y; o[2] = (__bf16)v.z; o[3] = (__bf16)v.w;
    outp[i] = o;
}

// ------- prep: build W_comb [2048][4096] bf16 in MFMA-fragment-swizzled order -------
// element (k, n): n = h*4+g ; k<1024 -> W_x{g}[k][h], else W_h{g}[k-1024][h]
// frag order: wf[(((ng*64 + kc)*64 + l)<<3) + j], kc=k>>5, quad=(k>>3)&3, j=k&7,
//             ng=n>>4, l=quad*16 + (n&15)   (B frag: lane holds col n=l&15, k=(l>>4)*8+j)
// UNCHANGED layout: a wave consuming slice ng just indexes wf + ng*64*64*8.
__global__ void build_w(const float* __restrict__ Wxi, const float* __restrict__ Whi,
                        const float* __restrict__ Wxf, const float* __restrict__ Whf,
                        const float* __restrict__ Wxc, const float* __restrict__ Whc,
                        const float* __restrict__ Wxo, const float* __restrict__ Who,
                        __bf16* __restrict__ wf) {
    int idx = blockIdx.x * 256 + threadIdx.x;    // 32768 * 256 = 2048*4096
    int k = idx >> 12, n = idx & 4095;
    int h = n >> 2, g = n & 3;
    const float* W;
    if (k < 1024) W = (g == 0 ? Wxi : g == 1 ? Wxf : g == 2 ? Wxc : Wxo);
    else          W = (g == 0 ? Whi : g == 1 ? Whf : g == 2 ? Whc : Who);
    float v = W[(k & 1023) * 1024 + h];
    int kc = k >> 5, quad = (k >> 3) & 3, j = k & 7;
    int ng = n >> 4, l = quad * 16 + (n & 15);
    wf[((((ng * 64) + kc) * 64 + l) << 3) + j] = (__bf16)v;
}

// ---------------- persistent recurrent kernel: 4 INDEPENDENT batch-groups ----------------
// Batches are independent in an LSTM: h(t+1)[b] depends only on h(t)[b].
// 256 blocks = 4 groups x 64 blocks. Group g owns batches g*16..g*16+15.
// Block bl (within group) owns gate-cols bl*64..+63 (= h-cols bl*16..+15);
// wave w holds weight slice ng = bl*4+w (64 KB in regs, same as before).
// Sync is now PER GROUP (64 blocks): 4x smaller barrier, groups fully decoupled,
// and each block broadcasts/reads only 32 KB of h + 32 KB of x per step (was 256 KB).
//
// h exchange: agent-scope (L2-bypassing) u64 stores into a per-group 64-slot ring at
// L3; readers use PLAIN vector loads — safe because per-L2 intervening fills
// (4 groups x (32KB x + 32KB ring) = 256 KB/step x 64 steps = 16 MB >> 4 MB L2)
// evict any copy of a slot before it is reused. One __threadfence per block at
// START (global flush round over all 256 blocks) clears harness-memset dirt.
__global__ void __launch_bounds__(256, 1) lstm_rnn(
    const __bf16* __restrict__ xbf,   // [64][512][1024]
    const __bf16* __restrict__ wf,    // frag-swizzled [256][64][64][8]
    const float* __restrict__ bi, const float* __restrict__ bfg,
    const float* __restrict__ bc, const float* __restrict__ bo,
    __bf16* __restrict__ ring,        // [4 groups][64 slots][16][1024] bf16 = 8 MB
    int* __restrict__ bar,            // 64 global-flush counters, 16-int stride
    int* __restrict__ gbar,           // 4*16 group counters, 16-int stride
    float* __restrict__ out)
{
    const int blk = blockIdx.x, tid = threadIdx.x;
    const int g = blk >> 6, bl = blk & 63;        // group, block-in-group
    const int wave = tid >> 6, lane = tid & 63;
    const int l15 = lane & 15, quad = lane >> 4;

    // preload this wave's W slice (ng = bl*4+wave) into registers: 64 chunks x 16B
    bf16x8 wfrag[64];
    const bf16x8* wsrc = (const bf16x8*)(wf + (size_t)(bl * 4 + wave) * (64 * 64 * 8));
    #pragma unroll
    for (int kc = 0; kc < 64; ++kc)
        wfrag[kc] = wsrc[kc * 64 + lane];

    // ---- round 1: GLOBAL flush of every XCD's L2 (memset-poison dirt) ----
    __threadfence();
    __syncthreads();
    if (tid == 0)
        __hip_atomic_fetch_add(&bar[(blk & 63) * 16], 1,
                               __ATOMIC_RELAXED, __HIP_MEMORY_SCOPE_AGENT);
    if (tid < 64) {
        while (__hip_atomic_load(&bar[tid * 16], __ATOMIC_RELAXED,
                                 __HIP_MEMORY_SCOPE_AGENT) < 4)
            __builtin_amdgcn_s_sleep(2);
    }
    __syncthreads();

    // ---- publish h0 = 0 into this group's ring slot 0 (after all flushes) ----
    u64* ring64 = (u64*)ring;
    const size_t gbase64 = (size_t)g * (64 * 4096);   // group base, u64 units
    if (tid < 64) {
        int batch = tid >> 2, part = tid & 3;
        __hip_atomic_store(ring64 + gbase64 + batch * 256 + bl * 4 + part, 0ULL,
                           __ATOMIC_RELAXED, __HIP_MEMORY_SCOPE_AGENT);
    }
    __builtin_amdgcn_s_waitcnt(0);
    __syncthreads();
    int* gcnt = gbar + (g * 16 + (bl & 15)) * 16;     // 4 blocks per counter
    if (tid == 0)
        __hip_atomic_fetch_add(gcnt, 1, __ATOMIC_RELAXED, __HIP_MEMORY_SCOPE_AGENT);

    // pointwise ownership: thread -> (batch pb of 16, local h-col phl of 16)
    const int pb = tid >> 4, phl = tid & 15;
    const int hcol = bl * 16 + phl;                   // global h-col
    const int bglob = g * 16 + pb;                    // global batch
    const float bias_i = bi[hcol], bias_f = bfg[hcol],
                bias_c = bc[hcol], bias_o = bo[hcol];
    float c_reg = 0.f;

    __shared__ float gates[16 * 65];   // [batch 16][64 gate-cols], pad 65 (reads conflict-free)
    __shared__ u64 hstage[64];         // [batch 16][4 parts] of 4x bf16

    // A-frag row = batch-in-group = l15 (all 4 waves share the same 16 batches)
    const __bf16* xrow_base = xbf + ((size_t)(g * 16 + l15) * 512) * 1024 + quad * 8;
    const __bf16* ringg = ring + (size_t)g * (64 * 16384);
    int* pollp = (tid < 16) ? (gbar + (g * 16 + tid) * 16) : gbar;

    for (int t = 0; t < 512; ++t) {
        // ---- x-part: no h dependency, overlaps group-straggler skew ----
        f32x4 acc0a = {0.f,0.f,0.f,0.f}, acc0b = {0.f,0.f,0.f,0.f};
        const __bf16* xrow = xrow_base + (size_t)t * 1024;
        #pragma unroll
        for (int kc = 0; kc < 16; ++kc) {
            bf16x8 a0 = *(const bf16x8*)(xrow + (2*kc) * 32);
            bf16x8 a1 = *(const bf16x8*)(xrow + (2*kc+1) * 32);
            acc0a = __builtin_amdgcn_mfma_f32_16x16x32_bf16(a0, wfrag[2*kc],   acc0a, 0,0,0);
            acc0b = __builtin_amdgcn_mfma_f32_16x16x32_bf16(a1, wfrag[2*kc+1], acc0b, 0,0,0);
        }

        // ---- wait: all 64 blocks of THIS group published h(t) (round t+1) ----
        const int target = 4 * (t + 1);
        if (tid < 16) {
            while (__hip_atomic_load(pollp, __ATOMIC_RELAXED,
                                     __HIP_MEMORY_SCOPE_AGENT) < target)
                __builtin_amdgcn_s_sleep(2);
        }
        __syncthreads();

        // ---- h-part: PLAIN pipelined vector loads from cold group ring slot ----
        f32x4 acc1a = {0.f,0.f,0.f,0.f}, acc1b = {0.f,0.f,0.f,0.f};
        const __bf16* hrow = ringg + (size_t)(t & 63) * 16384 + l15 * 1024 + quad * 8;
        #pragma unroll
        for (int kc = 0; kc < 16; ++kc) {
            bf16x8 a0 = *(const bf16x8*)(hrow + (2*kc) * 32);
            bf16x8 a1 = *(const bf16x8*)(hrow + (2*kc+1) * 32);
            acc1a = __builtin_amdgcn_mfma_f32_16x16x32_bf16(a0, wfrag[32+2*kc],   acc1a, 0,0,0);
            acc1b = __builtin_amdgcn_mfma_f32_16x16x32_bf16(a1, wfrag[32+2*kc+1], acc1b, 0,0,0);
        }

        // C/D frag: row = quad*4 + r (batch), col = l15; wave's cols at wave*16+l15
        #pragma unroll
        for (int r = 0; r < 4; ++r)
            gates[(quad * 4 + r) * 65 + wave * 16 + l15] =
                acc0a[r] + acc0b[r] + acc1a[r] + acc1b[r];
        __syncthreads();

        float gi = gates[pb * 65 + phl * 4 + 0] + bias_i;
        float gf = gates[pb * 65 + phl * 4 + 1] + bias_f;
        float gc = gates[pb * 65 + phl * 4 + 2] + bias_c;
        float go = gates[pb * 65 + phl * 4 + 3] + bias_o;
        float it = 1.f / (1.f + __expf(-gi));
        float ft = 1.f / (1.f + __expf(-gf));
        float ch = tanhf(gc);
        float ot = 1.f / (1.f + __expf(-go));
        c_reg = ft * c_reg + it * ch;
        float hn = ot * tanhf(c_reg);
        ((__bf16*)&hstage[pb * 4 + (phl >> 2)])[phl & 3] = (__bf16)hn;
        __syncthreads();   // hstage complete

        if (t < 511) {
            if (tid < 64) {
                // h(t+1): batch tid>>2, cols bl*16 + (tid&3)*4 .. +3 -> slot (t+1)&63
                u64 hv = hstage[tid];
                int batch = tid >> 2, part = tid & 3;
                __hip_atomic_store(ring64 + gbase64 + (size_t)((t + 1) & 63) * 4096
                                       + batch * 256 + bl * 4 + part,
                                   hv, __ATOMIC_RELAXED, __HIP_MEMORY_SCOPE_AGENT);
            }
            __builtin_amdgcn_s_waitcnt(0);   // ring stores at coherence point (only)
            __syncthreads();
            if (tid == 0)
                __hip_atomic_fetch_add(gcnt, 1, __ATOMIC_RELAXED,
                                       __HIP_MEMORY_SCOPE_AGENT);
        }

        // ---- out store DEFERRED past publish: its HBM write-ack is off the
        //      critical path (retired long before next step's s_waitcnt(0)) ----
        __builtin_nontemporal_store(hn, &out[((size_t)bglob * 512 + t) * 1024 + hcol]);
        if (t == 511) {
            __builtin_nontemporal_store(hn,    &out[OUT_HT + bglob * 1024 + hcol]);
            __builtin_nontemporal_store(c_reg, &out[OUT_CT + bglob * 1024 + hcol]);
        }
    }
}

extern "C" void kernel_launch(void* const* d_in, const int* in_sizes, int n_in,
                              void* d_out, int out_size, void* d_ws, size_t ws_size,
                              hipStream_t stream) {
    const float* x   = (const float*)d_in[0];
    const float* Wxi = (const float*)d_in[1];
    const float* Whi = (const float*)d_in[2];
    const float* bi  = (const float*)d_in[3];
    const float* Wxf = (const float*)d_in[4];
    const float* Whf = (const float*)d_in[5];
    const float* bfg = (const float*)d_in[6];
    const float* Wxc = (const float*)d_in[7];
    const float* Whc = (const float*)d_in[8];
    const float* bc  = (const float*)d_in[9];
    const float* Wxo = (const float*)d_in[10];
    const float* Who = (const float*)d_in[11];
    const float* bo  = (const float*)d_in[12];
    float* out = (float*)d_out;

    char* ws = (char*)d_ws;
    __bf16* wcombF = (__bf16*)ws;                        // 16 MB
    __bf16* xbf    = (__bf16*)(ws + (16ll << 20));       // 64 MB
    __bf16* ring   = (__bf16*)(ws + (80ll << 20));       // 4 groups x 64 slots x 32 KB = 8 MB
    int*    bar    = (int*)(ws + (88ll << 20));          // 64 x 64B flush counters
    int*    gbar   = (int*)(ws + (88ll << 20) + 4096);   // 4*16 x 64B group counters

    hipMemsetAsync(bar, 0, 8192, stream);                // bar + gbar

    hipLaunchKernelGGL(convert_x, dim3(32768), dim3(256), 0, stream,
                       (const float4*)x, (bf16x4*)xbf);
    hipLaunchKernelGGL(build_w, dim3(32768), dim3(256), 0, stream,
                       Wxi, Whi, Wxf, Whf, Wxc, Whc, Wxo, Who, wcombF);

    hipLaunchKernelGGL(lstm_rnn, dim3(256), dim3(256), 0, stream,
                       xbf, wcombF, bi, bfg, bc, bo, ring, bar, gbar, out);
}